// Round 5
// baseline (211.493 us; speedup 1.0000x reference)
//
#include <hip/hip_runtime.h>
#include <hip/hip_bf16.h>
#include <stdint.h>

#define N_PTS 262144
#define KOFF 27
#define CIN 64
#define COUT 64
#define EPS 1e-5f

typedef __attribute__((ext_vector_type(8))) short short8;
typedef __attribute__((ext_vector_type(4))) float f32x4;
typedef __attribute__((ext_vector_type(4))) unsigned short ushort4v;

static __device__ __forceinline__ unsigned short f32_to_bf16(float f) {
    union { float f; unsigned int u; } v; v.f = f;
    unsigned int u = v.u;
    unsigned int rounded = u + 0x7FFF + ((u >> 16) & 1);
    return (unsigned short)(rounded >> 16);
}

// ---- P0: pack weight [27][64][64] f32 -> bf16 MFMA B-fragment order ----
// pw[k][s][t][lane][e]: B[k_local=(lane>>4)*8+e][col=lane&15], cin=s*32+k_local, cout=t*16+col
__global__ void k_packW(const float* __restrict__ w, unsigned short* __restrict__ pw) {
    int tid = blockIdx.x * blockDim.x + threadIdx.x;
    if (tid >= KOFF * 4096) return;
    int e = tid & 7;
    int l = (tid >> 3) & 63;
    int t = (tid >> 9) & 3;
    int s = (tid >> 11) & 1;
    int k = tid >> 12;
    int cin  = s * 32 + (l >> 4) * 8 + e;
    int cout = t * 16 + (l & 15);
    pw[tid] = f32_to_bf16(w[(k * CIN + cin) * COUT + cout]);
}

// ---- P1: features f32 -> bf16, with zero pad row at index N ----
__global__ void k_feat2bf16(const float* __restrict__ feat, unsigned short* __restrict__ out) {
    int gid = blockIdx.x * blockDim.x + threadIdx.x;
    const int total4 = (N_PTS + 1) * CIN / 4;
    if (gid >= total4) return;
    int base = gid * 4;
    ushort4v o;
    if (base < N_PTS * CIN) {
        f32x4 f = *reinterpret_cast<const f32x4*>(feat + base);
        o[0] = f32_to_bf16(f[0]); o[1] = f32_to_bf16(f[1]);
        o[2] = f32_to_bf16(f[2]); o[3] = f32_to_bf16(f[3]);
    } else {
        o[0] = 0; o[1] = 0; o[2] = 0; o[3] = 0;
    }
    *reinterpret_cast<ushort4v*>(out + base) = o;
}

// ---- M: gather + MFMA GEMM. Barrier-free, LDS-free, per-wave independent ----
// 128 thr = 2 independent waves, 32 rows/wave. 4096 blocks (2x oversubscribed).
// Per iter kk: [load B(kk-1) -> bn (8 coalesced, L2-hit)] [gather A(kk) -> t (4)]
//              [idx(kk+2) (2)] | MFMA(kk-2) on bc=B(kk-2), ac=A(kk-2).
// Queue math (in-order vmcnt): MFMA's wait for bc (issued last iter, pos 0-7)
// = vmcnt(20), which retires ac (older) exactly on time and leaves
// A(kk-1), B(kk-1), A(kk) in flight -> gathers get 2 full iterations of cover.
__global__ __launch_bounds__(128, 3) void k_conv(
    const unsigned short* __restrict__ feat,   // (N+1) x 64 bf16
    const int* __restrict__ nbr,               // 27 x N
    const unsigned short* __restrict__ pw,     // packed weights (bf16 frag order)
    float* __restrict__ conv_out,              // N x 64 (pre-BN)
    float* __restrict__ grp)                   // 64 x 128 f32 (sum | sumsq), pre-zeroed
{
    const int tid = threadIdx.x;
    const int l  = tid & 63;
    const int w  = tid >> 6;
    const int lr = l & 15;      // A row within 16 / C col within 16
    const int lg = l >> 4;      // cin-slice group / C row group
    const int wid = blockIdx.x * 2 + w;        // 0..8191
    const int rowbase = wid * 32;
    const int r0 = rowbase + lr;
    const int r1 = r0 + 16;
    const int lane_cin = lg * 8;

    f32x4 acc[2][4] = {};
    const short8* pwv = reinterpret_cast<const short8*>(pw);

    // idx pipeline: ia = idx[kk] (ready), ib = idx[kk+1] (in flight)
    int ia0 = nbr[r0],          ia1 = nbr[r1];
    int ib0 = nbr[N_PTS + r0],  ib1 = nbr[N_PTS + r1];

    // A pipeline: ac = A(kk-2) (consume), an = A(kk-1), t = A(kk) (loading)
    short8 ac0 = {}, ac1 = {}, ac2 = {}, ac3 = {};
    short8 an0 = {}, an1 = {}, an2 = {}, an3 = {};
    // B pipeline: bc = B(kk-2) (consume), bn = B(kk-1) (loading)
    short8 bc0 = {}, bc1 = {}, bc2 = {}, bc3 = {}, bc4 = {}, bc5 = {}, bc6 = {}, bc7 = {};
    short8 bn0 = {}, bn1 = {}, bn2 = {}, bn3 = {}, bn4 = {}, bn5 = {}, bn6 = {}, bn7 = {};

    #pragma unroll
    for (int kk = 0; kk < KOFF + 2; ++kk) {
        // ---- issue phase (order pinned by sched_barrier fences) ----
        if (kk >= 1 && kk - 1 < KOFF) {   // B(kk-1) -> bn
            const short8* bb = pwv + (kk - 1) * 512 + l;
            bn0 = bb[0];   bn1 = bb[64];  bn2 = bb[128]; bn3 = bb[192];
            bn4 = bb[256]; bn5 = bb[320]; bn6 = bb[384]; bn7 = bb[448];
        }
        short8 t0 = {}, t1 = {}, t2 = {}, t3 = {};
        if (kk < KOFF) {                  // gather A(kk) using ia = idx[kk]
            const short8* g0 = reinterpret_cast<const short8*>(feat + ia0 * 64 + lane_cin);
            const short8* g1 = reinterpret_cast<const short8*>(feat + ia1 * 64 + lane_cin);
            t0 = g0[0]; t1 = g0[4]; t2 = g1[0]; t3 = g1[4];
        }
        int ic0 = 0, ic1 = 0;
        if (kk + 2 < KOFF) {              // idx[kk+2]
            ic0 = nbr[(kk + 2) * N_PTS + r0];
            ic1 = nbr[(kk + 2) * N_PTS + r1];
        }
        __builtin_amdgcn_sched_barrier(0);

        if (kk >= 2) {
            // 16 MFMA on bc (B(kk-2)) and ac (A(kk-2))
            acc[0][0] = __builtin_amdgcn_mfma_f32_16x16x32_bf16(ac0, bc0, acc[0][0], 0, 0, 0);
            acc[1][0] = __builtin_amdgcn_mfma_f32_16x16x32_bf16(ac2, bc0, acc[1][0], 0, 0, 0);
            acc[0][1] = __builtin_amdgcn_mfma_f32_16x16x32_bf16(ac0, bc1, acc[0][1], 0, 0, 0);
            acc[1][1] = __builtin_amdgcn_mfma_f32_16x16x32_bf16(ac2, bc1, acc[1][1], 0, 0, 0);
            acc[0][2] = __builtin_amdgcn_mfma_f32_16x16x32_bf16(ac0, bc2, acc[0][2], 0, 0, 0);
            acc[1][2] = __builtin_amdgcn_mfma_f32_16x16x32_bf16(ac2, bc2, acc[1][2], 0, 0, 0);
            acc[0][3] = __builtin_amdgcn_mfma_f32_16x16x32_bf16(ac0, bc3, acc[0][3], 0, 0, 0);
            acc[1][3] = __builtin_amdgcn_mfma_f32_16x16x32_bf16(ac2, bc3, acc[1][3], 0, 0, 0);
            acc[0][0] = __builtin_amdgcn_mfma_f32_16x16x32_bf16(ac1, bc4, acc[0][0], 0, 0, 0);
            acc[1][0] = __builtin_amdgcn_mfma_f32_16x16x32_bf16(ac3, bc4, acc[1][0], 0, 0, 0);
            acc[0][1] = __builtin_amdgcn_mfma_f32_16x16x32_bf16(ac1, bc5, acc[0][1], 0, 0, 0);
            acc[1][1] = __builtin_amdgcn_mfma_f32_16x16x32_bf16(ac3, bc5, acc[1][1], 0, 0, 0);
            acc[0][2] = __builtin_amdgcn_mfma_f32_16x16x32_bf16(ac1, bc6, acc[0][2], 0, 0, 0);
            acc[1][2] = __builtin_amdgcn_mfma_f32_16x16x32_bf16(ac3, bc6, acc[1][2], 0, 0, 0);
            acc[0][3] = __builtin_amdgcn_mfma_f32_16x16x32_bf16(ac1, bc7, acc[0][3], 0, 0, 0);
            acc[1][3] = __builtin_amdgcn_mfma_f32_16x16x32_bf16(ac3, bc7, acc[1][3], 0, 0, 0);
        }
        __builtin_amdgcn_sched_barrier(0);

        // rotate pipelines (register renaming under full unroll)
        ia0 = ib0; ia1 = ib1; ib0 = ic0; ib1 = ic1;
        ac0 = an0; ac1 = an1; ac2 = an2; ac3 = an3;
        an0 = t0;  an1 = t1;  an2 = t2;  an3 = t3;
        bc0 = bn0; bc1 = bn1; bc2 = bn2; bc3 = bn3;
        bc4 = bn4; bc5 = bn5; bc6 = bn6; bc7 = bn7;
    }

    // ---- epilogue: store conv (f32) + wave-internal channel stats ----
    const int orow_base = rowbase + lg * 4;   // C row = lg*4 + e (+ m*16)
    float psum[4], psq[4];
    #pragma unroll
    for (int t = 0; t < 4; ++t) {
        const int c = t * 16 + lr;            // C col = lane&15
        float s = 0.f, q = 0.f;
        #pragma unroll
        for (int m = 0; m < 2; ++m) {
            #pragma unroll
            for (int e = 0; e < 4; ++e) {
                float v = acc[m][t][e];
                conv_out[(orow_base + m * 16 + e) * 64 + c] = v;
                s += v; q += v * v;
            }
        }
        psum[t] = s; psq[t] = q;
    }
    // reduce across the 4 lg-groups (lanes lg*16+lr share channel c)
    #pragma unroll
    for (int t = 0; t < 4; ++t) {
        psum[t] += __shfl_xor(psum[t], 16, 64);
        psum[t] += __shfl_xor(psum[t], 32, 64);
        psq[t]  += __shfl_xor(psq[t],  16, 64);
        psq[t]  += __shfl_xor(psq[t],  32, 64);
    }
    if (lg == 0) {
        float* g = grp + (blockIdx.x & 63) * 128;
        #pragma unroll
        for (int t = 0; t < 4; ++t) {
            const int c = t * 16 + lr;
            atomicAdd(&g[c],      psum[t]);
            atomicAdd(&g[64 + c], psq[t]);
        }
    }
}

// ---- S: reduce 64x128 group partials -> scale/shift per channel (1 block) ----
__global__ void k_stats(const float* __restrict__ grp,
                        const float* __restrict__ gamma,
                        const float* __restrict__ beta,
                        float* __restrict__ ss) {
    __shared__ float red[128];
    const int j = threadIdx.x;    // 0..127
    float s = 0.f;
    for (int g = 0; g < 64; ++g) s += grp[g * 128 + j];
    red[j] = s;
    __syncthreads();
    if (j < 64) {
        float mean  = red[j] / (float)N_PTS;
        float var   = red[64 + j] / (float)N_PTS - mean * mean;
        float scale = gamma[j] * rsqrtf(var + EPS);
        ss[j]      = scale;
        ss[64 + j] = beta[j] - mean * scale;
    }
}

// ---- F: in-place BN affine + ReLU on d_out ----
__global__ void k_bnrelu(float* __restrict__ out, const float* __restrict__ ss) {
    int gid = blockIdx.x * blockDim.x + threadIdx.x;   // N*64/4 threads
    int base = gid * 4;
    int c0 = base & 63;
    f32x4 v  = *reinterpret_cast<f32x4*>(out + base);
    f32x4 sc = *reinterpret_cast<const f32x4*>(ss + c0);
    f32x4 sh = *reinterpret_cast<const f32x4*>(ss + 64 + c0);
    f32x4 r;
    #pragma unroll
    for (int j = 0; j < 4; ++j) r[j] = fmaxf(v[j] * sc[j] + sh[j], 0.f);
    *reinterpret_cast<f32x4*>(out + base) = r;
}

extern "C" void kernel_launch(void* const* d_in, const int* in_sizes, int n_in,
                              void* d_out, int out_size, void* d_ws, size_t ws_size,
                              hipStream_t stream) {
    const float* features = (const float*)d_in[0];
    const int*   nbr      = (const int*)d_in[1];
    const float* weight   = (const float*)d_in[2];
    const float* gamma    = (const float*)d_in[3];
    const float* beta     = (const float*)d_in[4];
    float* out = (float*)d_out;
    char* ws = (char*)d_ws;

    const size_t off_feat = 0;                                   // (N+1)*64 bf16
    const size_t off_pw   = 33554560;                            // 27*4096 bf16
    const size_t off_grp  = off_pw + 221184;                     // 64*128 f32 = 32 KB
    const size_t off_ss   = off_grp + 32768;                     // 128 f32
    unsigned short* feat16 = (unsigned short*)(ws + off_feat);
    unsigned short* pw     = (unsigned short*)(ws + off_pw);
    float*          grp    = (float*)(ws + off_grp);
    float*          ss     = (float*)(ws + off_ss);

    hipMemsetAsync(grp, 0, 64 * 128 * sizeof(float), stream);    // fresh stats each call
    k_packW<<<(KOFF * 4096 + 255) / 256, 256, 0, stream>>>(weight, pw);
    k_feat2bf16<<<((N_PTS + 1) * CIN / 4 + 255) / 256, 256, 0, stream>>>(features, feat16);
    k_conv<<<N_PTS / 64, 128, 0, stream>>>(feat16, nbr, pw, out, grp);
    k_stats<<<1, 128, 0, stream>>>(grp, gamma, beta, ss);
    k_bnrelu<<<N_PTS * COUT / 4 / 256, 256, 0, stream>>>(out, ss);
}

// Round 6
// 191.013 us; speedup vs baseline: 1.1072x; 1.1072x over previous
//
#include <hip/hip_runtime.h>
#include <hip/hip_bf16.h>
#include <stdint.h>

#define N_PTS 262144
#define KOFF 27
#define CIN 64
#define COUT 64
#define EPS 1e-5f

typedef __attribute__((ext_vector_type(8))) short short8;
typedef __attribute__((ext_vector_type(4))) float f32x4;
typedef __attribute__((ext_vector_type(4))) unsigned short ushort4v;

typedef __attribute__((address_space(3))) unsigned int lds_u32;
typedef __attribute__((address_space(1))) const unsigned int glb_u32;
#define GLDS16(g, s) __builtin_amdgcn_global_load_lds((glb_u32*)(g), (lds_u32*)(s), 16, 0, 0)

static __device__ __forceinline__ unsigned short f32_to_bf16(float f) {
    union { float f; unsigned int u; } v; v.f = f;
    unsigned int u = v.u;
    unsigned int rounded = u + 0x7FFF + ((u >> 16) & 1);
    return (unsigned short)(rounded >> 16);
}

// ---- P0: pack weight [27][64][64] f32 -> bf16 MFMA B-fragment order ----
// pw[k][s][t][lane][e]: B[k_local=(lane>>4)*8+e][col=lane&15], cin=s*32+k_local, cout=t*16+col
__global__ void k_packW(const float* __restrict__ w, unsigned short* __restrict__ pw) {
    int tid = blockIdx.x * blockDim.x + threadIdx.x;
    if (tid >= KOFF * 4096) return;
    int e = tid & 7;
    int l = (tid >> 3) & 63;
    int t = (tid >> 9) & 3;
    int s = (tid >> 11) & 1;
    int k = tid >> 12;
    int cin  = s * 32 + (l >> 4) * 8 + e;
    int cout = t * 16 + (l & 15);
    pw[tid] = f32_to_bf16(w[(k * CIN + cin) * COUT + cout]);
}

// ---- P1: features f32 -> bf16, with zero pad row at index N ----
__global__ void k_feat2bf16(const float* __restrict__ feat, unsigned short* __restrict__ out) {
    int gid = blockIdx.x * blockDim.x + threadIdx.x;
    const int total4 = (N_PTS + 1) * CIN / 4;
    if (gid >= total4) return;
    int base = gid * 4;
    ushort4v o;
    if (base < N_PTS * CIN) {
        f32x4 f = *reinterpret_cast<const f32x4*>(feat + base);
        o[0] = f32_to_bf16(f[0]); o[1] = f32_to_bf16(f[1]);
        o[2] = f32_to_bf16(f[2]); o[3] = f32_to_bf16(f[3]);
    } else {
        o[0] = 0; o[1] = 0; o[2] = 0; o[3] = 0;
    }
    *reinterpret_cast<ushort4v*>(out + base) = o;
}

// ---- M: gather + MFMA GEMM, ring-buffered counted-vmcnt pipeline ----
// 256 thr = 4 waves, 128 rows/block, grid 2048. Per iter j (macro, literal slots):
//   issue [idx(j+2):2][glds B(j-1):2][gather A(j):4]  (8 vmem ops, uniform via clamps)
//   s_waitcnt vmcnt(12)  -> retires exactly B(j-2) + A(j-2); leaves 12 in flight
//   raw s_barrier (no drain) -> all waves' B(j-2) quarters visible
//   16 MFMA on a[(j-2)%3] and LDS slot (j-2)%3
// Ring-3 everywhere: no rotation copies, no dynamic register indexing, so the
// compiler cannot collapse the pipeline. Gathers get a 2-iteration window.
__global__ __launch_bounds__(256, 3) void k_conv(
    const unsigned short* __restrict__ feat,   // (N+1) x 64 bf16
    const int* __restrict__ nbr,               // 27 x N
    const unsigned short* __restrict__ pw,     // packed weights (bf16 frag order)
    float* __restrict__ conv_out,              // N x 64 (pre-BN, f32, = d_out)
    float* __restrict__ grp)                   // 64 x 128 f32 (sum | sumsq), pre-zeroed
{
    __shared__ short8 ldsB[3][512];            // 3 x 8 KB B ring

    const int tid = threadIdx.x;
    const int l  = tid & 63;
    const int w  = tid >> 6;
    const int lr = l & 15;      // A row within 16 / C col within 16
    const int lg = l >> 4;      // cin-slice group / C row group
    const int rowbase = blockIdx.x * 128 + w * 32;
    const int r0 = rowbase + lr;
    const int r1 = r0 + 16;
    const int lane_cin = lg * 8;

    f32x4 acc[2][4] = {};
    const short8* pwv = reinterpret_cast<const short8*>(pw);

    int   idxr[3][2];
    short8 a[3][4];

    // ---- prologue ----
    // idx[0]->slot0, idx[1]->slot1
    idxr[0][0] = nbr[r0];          idxr[0][1] = nbr[r1];
    idxr[1][0] = nbr[N_PTS + r0];  idxr[1][1] = nbr[N_PTS + r1];
    // j=0: idx[2]->slot2 ; gather A(0)->slot0
    idxr[2][0] = nbr[2 * N_PTS + r0]; idxr[2][1] = nbr[2 * N_PTS + r1];
    {
        const short8* g0 = reinterpret_cast<const short8*>(feat + (long)idxr[0][0] * 64 + lane_cin);
        const short8* g1 = reinterpret_cast<const short8*>(feat + (long)idxr[0][1] * 64 + lane_cin);
        a[0][0] = g0[0]; a[0][1] = g0[4]; a[0][2] = g1[0]; a[0][3] = g1[4];
    }
    // j=1: idx[3]->slot0 ; glds B(0)->LDS slot0 ; gather A(1)->slot1
    idxr[0][0] = nbr[3 * N_PTS + r0]; idxr[0][1] = nbr[3 * N_PTS + r1];
    GLDS16(pwv + w * 128 + l,      &ldsB[0][w * 128]);
    GLDS16(pwv + w * 128 + 64 + l, &ldsB[0][w * 128 + 64]);
    {
        const short8* g0 = reinterpret_cast<const short8*>(feat + (long)idxr[1][0] * 64 + lane_cin);
        const short8* g1 = reinterpret_cast<const short8*>(feat + (long)idxr[1][1] * 64 + lane_cin);
        a[1][0] = g0[0]; a[1][1] = g0[4]; a[1][2] = g1[0]; a[1][3] = g1[4];
    }

    // ---- steady-state step: P0 = j%3 (literal); P1 = consume, P2 = stage ----
#define STEP(JV, P0, P1, P2) do {                                              \
        const int j_ = (JV);                                                   \
        const int kI = (j_ + 2 <= KOFF - 1) ? j_ + 2 : KOFF - 1;               \
        idxr[P2][0] = nbr[kI * N_PTS + r0];                                    \
        idxr[P2][1] = nbr[kI * N_PTS + r1];                                    \
        const int kB = (j_ - 1 <= KOFF - 1) ? j_ - 1 : KOFF - 1;               \
        GLDS16(pwv + kB * 512 + w * 128 + l,      &ldsB[P2][w * 128]);         \
        GLDS16(pwv + kB * 512 + w * 128 + 64 + l, &ldsB[P2][w * 128 + 64]);    \
        {                                                                      \
            const short8* g0 = reinterpret_cast<const short8*>(feat + (long)idxr[P0][0] * 64 + lane_cin); \
            const short8* g1 = reinterpret_cast<const short8*>(feat + (long)idxr[P0][1] * 64 + lane_cin); \
            a[P0][0] = g0[0]; a[P0][1] = g0[4];                                \
            a[P0][2] = g1[0]; a[P0][3] = g1[4];                                \
        }                                                                      \
        asm volatile("s_waitcnt vmcnt(12)" ::: "memory");                      \
        __builtin_amdgcn_s_barrier();                                          \
        {                                                                      \
            const short8* cb = &ldsB[P1][0];                                   \
            short8 b0 = cb[l];       short8 b1 = cb[64 + l];                   \
            short8 b2 = cb[128 + l]; short8 b3 = cb[192 + l];                  \
            short8 b4 = cb[256 + l]; short8 b5 = cb[320 + l];                  \
            short8 b6 = cb[384 + l]; short8 b7 = cb[448 + l];                  \
            acc[0][0] = __builtin_amdgcn_mfma_f32_16x16x32_bf16(a[P1][0], b0, acc[0][0], 0, 0, 0); \
            acc[1][0] = __builtin_amdgcn_mfma_f32_16x16x32_bf16(a[P1][2], b0, acc[1][0], 0, 0, 0); \
            acc[0][1] = __builtin_amdgcn_mfma_f32_16x16x32_bf16(a[P1][0], b1, acc[0][1], 0, 0, 0); \
            acc[1][1] = __builtin_amdgcn_mfma_f32_16x16x32_bf16(a[P1][2], b1, acc[1][1], 0, 0, 0); \
            acc[0][2] = __builtin_amdgcn_mfma_f32_16x16x32_bf16(a[P1][0], b2, acc[0][2], 0, 0, 0); \
            acc[1][2] = __builtin_amdgcn_mfma_f32_16x16x32_bf16(a[P1][2], b2, acc[1][2], 0, 0, 0); \
            acc[0][3] = __builtin_amdgcn_mfma_f32_16x16x32_bf16(a[P1][0], b3, acc[0][3], 0, 0, 0); \
            acc[1][3] = __builtin_amdgcn_mfma_f32_16x16x32_bf16(a[P1][2], b3, acc[1][3], 0, 0, 0); \
            acc[0][0] = __builtin_amdgcn_mfma_f32_16x16x32_bf16(a[P1][1], b4, acc[0][0], 0, 0, 0); \
            acc[1][0] = __builtin_amdgcn_mfma_f32_16x16x32_bf16(a[P1][3], b4, acc[1][0], 0, 0, 0); \
            acc[0][1] = __builtin_amdgcn_mfma_f32_16x16x32_bf16(a[P1][1], b5, acc[0][1], 0, 0, 0); \
            acc[1][1] = __builtin_amdgcn_mfma_f32_16x16x32_bf16(a[P1][3], b5, acc[1][1], 0, 0, 0); \
            acc[0][2] = __builtin_amdgcn_mfma_f32_16x16x32_bf16(a[P1][1], b6, acc[0][2], 0, 0, 0); \
            acc[1][2] = __builtin_amdgcn_mfma_f32_16x16x32_bf16(a[P1][3], b6, acc[1][2], 0, 0, 0); \
            acc[0][3] = __builtin_amdgcn_mfma_f32_16x16x32_bf16(a[P1][1], b7, acc[0][3], 0, 0, 0); \
            acc[1][3] = __builtin_amdgcn_mfma_f32_16x16x32_bf16(a[P1][3], b7, acc[1][3], 0, 0, 0); \
        }                                                                      \
    } while (0)

    // main loop: j = 2..28, step 3 (j%3 pattern 2,0,1) -> literal slots
    for (int jt = 0; jt < 9; ++jt) {
        const int j = 2 + jt * 3;
        STEP(j,     2, 0, 1);
        STEP(j + 1, 0, 1, 2);
        STEP(j + 2, 1, 2, 0);
    }
#undef STEP

    // ---- epilogue: store conv (f32) + wave-internal channel stats ----
    const int orow_base = rowbase + lg * 4;   // C row = lg*4 + e (+ m*16)
    float psum[4], psq[4];
    #pragma unroll
    for (int t = 0; t < 4; ++t) {
        const int c = t * 16 + lr;            // C col = lane&15
        float s = 0.f, q = 0.f;
        #pragma unroll
        for (int m = 0; m < 2; ++m) {
            #pragma unroll
            for (int e = 0; e < 4; ++e) {
                float v = acc[m][t][e];
                conv_out[(orow_base + m * 16 + e) * 64 + c] = v;
                s += v; q += v * v;
            }
        }
        psum[t] = s; psq[t] = q;
    }
    #pragma unroll
    for (int t = 0; t < 4; ++t) {
        psum[t] += __shfl_xor(psum[t], 16, 64);
        psum[t] += __shfl_xor(psum[t], 32, 64);
        psq[t]  += __shfl_xor(psq[t],  16, 64);
        psq[t]  += __shfl_xor(psq[t],  32, 64);
    }
    if (lg == 0) {
        float* g = grp + (blockIdx.x & 63) * 128;
        #pragma unroll
        for (int t = 0; t < 4; ++t) {
            const int c = t * 16 + lr;
            atomicAdd(&g[c],      psum[t]);
            atomicAdd(&g[64 + c], psq[t]);
        }
    }
}

// ---- S: reduce 64x128 group partials -> scale/shift per channel (1 block) ----
__global__ void k_stats(const float* __restrict__ grp,
                        const float* __restrict__ gamma,
                        const float* __restrict__ beta,
                        float* __restrict__ ss) {
    __shared__ float red[128];
    const int j = threadIdx.x;    // 0..127
    float s = 0.f;
    for (int g = 0; g < 64; ++g) s += grp[g * 128 + j];
    red[j] = s;
    __syncthreads();
    if (j < 64) {
        float mean  = red[j] / (float)N_PTS;
        float var   = red[64 + j] / (float)N_PTS - mean * mean;
        float scale = gamma[j] * rsqrtf(var + EPS);
        ss[j]      = scale;
        ss[64 + j] = beta[j] - mean * scale;
    }
}

// ---- F: in-place BN affine + ReLU on d_out ----
__global__ void k_bnrelu(float* __restrict__ out, const float* __restrict__ ss) {
    int gid = blockIdx.x * blockDim.x + threadIdx.x;   // N*64/4 threads
    int base = gid * 4;
    int c0 = base & 63;
    f32x4 v  = *reinterpret_cast<f32x4*>(out + base);
    f32x4 sc = *reinterpret_cast<const f32x4*>(ss + c0);
    f32x4 sh = *reinterpret_cast<const f32x4*>(ss + 64 + c0);
    f32x4 r;
    #pragma unroll
    for (int j = 0; j < 4; ++j) r[j] = fmaxf(v[j] * sc[j] + sh[j], 0.f);
    *reinterpret_cast<f32x4*>(out + base) = r;
}

extern "C" void kernel_launch(void* const* d_in, const int* in_sizes, int n_in,
                              void* d_out, int out_size, void* d_ws, size_t ws_size,
                              hipStream_t stream) {
    const float* features = (const float*)d_in[0];
    const int*   nbr      = (const int*)d_in[1];
    const float* weight   = (const float*)d_in[2];
    const float* gamma    = (const float*)d_in[3];
    const float* beta     = (const float*)d_in[4];
    float* out = (float*)d_out;
    char* ws = (char*)d_ws;

    const size_t off_feat = 0;                                   // (N+1)*64 bf16
    const size_t off_pw   = 33554560;                            // 27*4096 bf16
    const size_t off_grp  = off_pw + 221184;                     // 64*128 f32 = 32 KB
    const size_t off_ss   = off_grp + 32768;                     // 128 f32
    unsigned short* feat16 = (unsigned short*)(ws + off_feat);
    unsigned short* pw     = (unsigned short*)(ws + off_pw);
    float*          grp    = (float*)(ws + off_grp);
    float*          ss     = (float*)(ws + off_ss);

    hipMemsetAsync(grp, 0, 64 * 128 * sizeof(float), stream);    // fresh stats each call
    k_packW<<<(KOFF * 4096 + 255) / 256, 256, 0, stream>>>(weight, pw);
    k_feat2bf16<<<((N_PTS + 1) * CIN / 4 + 255) / 256, 256, 0, stream>>>(features, feat16);
    k_conv<<<N_PTS / 128, 256, 0, stream>>>(feat16, nbr, pw, out, grp);
    k_stats<<<1, 128, 0, stream>>>(grp, gamma, beta, ss);
    k_bnrelu<<<N_PTS * COUT / 4 / 256, 256, 0, stream>>>(out, ss);
}